// Round 1
// baseline (862.847 us; speedup 1.0000x reference)
//
#include <hip/hip_runtime.h>
#include <cstdint>
#include <cstddef>

// Problem constants
#define T_TOKENS 4096   // B*S
#define DDIM     1024
#define HDIM     4096
#define NEXP     8
#define MAXROWS  9216   // 8192 slots + 8*128 padding worst case
#define MAXTILES 72     // MAXROWS/128

typedef __attribute__((ext_vector_type(8))) short bf16x8;
typedef __attribute__((ext_vector_type(4))) float f32x4;

__device__ __forceinline__ unsigned short f2bf(float x) {
  union { float f; unsigned int u; } v; v.f = x;
  unsigned int r = v.u + 0x7fffu + ((v.u >> 16) & 1u);   // RNE
  return (unsigned short)(r >> 16);
}
__device__ __forceinline__ float bf2f(unsigned short b) {
  union { unsigned int u; float f; } v; v.u = ((unsigned int)b) << 16;
  return v.f;
}
__device__ __forceinline__ void async_cp16(const void* g, void* l) {
  __builtin_amdgcn_global_load_lds(
      (__attribute__((address_space(1))) void*)g,
      (__attribute__((address_space(3))) void*)l, 16, 0, 0);
}

// ---------------- router: logits, softmax, top-2, stats ----------------
__global__ __launch_bounds__(256)
void moe_router(const float* __restrict__ x, const float* __restrict__ rw,
                int* __restrict__ tk_idx, float* __restrict__ tk_prob,
                int* __restrict__ counts, float* __restrict__ meanprob) {
  __shared__ float sp[NEXP];
  __shared__ int   sc[NEXP];
  const int tid = threadIdx.x;
  if (tid < NEXP) { sp[tid] = 0.f; sc[tid] = 0; }
  __syncthreads();
  const int wave = tid >> 6, lane = tid & 63;
  const int t = blockIdx.x * 4 + wave;
  float acc[NEXP] = {};
  for (int i = 0; i < 16; ++i) {
    const int d = i * 64 + lane;
    const float xv = x[(size_t)t * DDIM + d];
#pragma unroll
    for (int e = 0; e < NEXP; ++e) acc[e] += xv * rw[e * DDIM + d];
  }
#pragma unroll
  for (int e = 0; e < NEXP; ++e) {
#pragma unroll
    for (int m = 32; m >= 1; m >>= 1) acc[e] += __shfl_xor(acc[e], m);
  }
  if (lane == 0) {
    float mx = acc[0];
#pragma unroll
    for (int e = 1; e < NEXP; ++e) mx = fmaxf(mx, acc[e]);
    float p[NEXP], s = 0.f;
#pragma unroll
    for (int e = 0; e < NEXP; ++e) { p[e] = expf(acc[e] - mx); s += p[e]; }
    const float inv = 1.f / s;
#pragma unroll
    for (int e = 0; e < NEXP; ++e) p[e] *= inv;
    int i0 = 0;
#pragma unroll
    for (int e = 1; e < NEXP; ++e) if (p[e] > p[i0]) i0 = e;
    int i1 = (i0 == 0) ? 1 : 0;
#pragma unroll
    for (int e = 0; e < NEXP; ++e) if (e != i0 && p[e] > p[i1]) i1 = e;
    const float dn = 1.f / (p[i0] + p[i1] + 1e-8f);
    tk_idx[2 * t] = i0; tk_idx[2 * t + 1] = i1;
    tk_prob[2 * t] = p[i0] * dn; tk_prob[2 * t + 1] = p[i1] * dn;
#pragma unroll
    for (int e = 0; e < NEXP; ++e) atomicAdd(&sp[e], p[e]);
    atomicAdd(&sc[i0], 1); atomicAdd(&sc[i1], 1);
  }
  __syncthreads();
  if (tid < NEXP) {
    atomicAdd(&counts[tid], sc[tid]);
    atomicAdd(&meanprob[tid], sp[tid]);
  }
}

// ---------------- prep: padded offsets, cursors, loss ----------------
__global__ void moe_prep(const int* __restrict__ counts, int* __restrict__ cursor,
                         int* __restrict__ off, const float* __restrict__ meanprob,
                         float* __restrict__ loss_out) {
  if (threadIdx.x == 0) {
    int o = 0;
    float loss = 0.f;
    off[0] = 0;
    for (int e = 0; e < NEXP; ++e) {
      const int c = counts[e];
      cursor[e] = o;
      loss += meanprob[e] * (float)c;
      o += (c + 127) & ~127;
      off[e + 1] = o;
    }
    // E * sum( (meanprob/T) * (count/(T*K)) )
    loss_out[0] = loss * (8.f / (4096.f * 8192.f));
  }
}

// ---------------- scatter: gather x rows -> bf16 slots ----------------
__global__ __launch_bounds__(64)
void moe_scatter(const float* __restrict__ x, const int* __restrict__ tk_idx,
                 int* __restrict__ cursor, int* __restrict__ slot_of,
                 unsigned short* __restrict__ Xg) {
  const int t = blockIdx.x;
  const int lane = threadIdx.x;
  int pos0 = 0, pos1 = 0;
  if (lane == 0) {
    const int e0 = tk_idx[2 * t], e1 = tk_idx[2 * t + 1];
    pos0 = atomicAdd(&cursor[e0], 1);
    pos1 = atomicAdd(&cursor[e1], 1);
    slot_of[2 * t] = pos0; slot_of[2 * t + 1] = pos1;
  }
  pos0 = __shfl(pos0, 0);
  pos1 = __shfl(pos1, 0);
#pragma unroll
  for (int i = 0; i < 4; ++i) {
    const int d4 = (i * 64 + lane) * 4;
    const float4 f = *(const float4*)(x + (size_t)t * DDIM + d4);
    ushort4 u;
    u.x = f2bf(f.x); u.y = f2bf(f.y); u.z = f2bf(f.z); u.w = f2bf(f.w);
    *(ushort4*)(Xg + (size_t)pos0 * DDIM + d4) = u;
    *(ushort4*)(Xg + (size_t)pos1 * DDIM + d4) = u;
  }
}

// ---------------- zero the padding rows ----------------
__global__ __launch_bounds__(256)
void moe_padzero(const int* __restrict__ off, const int* __restrict__ counts,
                 unsigned short* __restrict__ Xg) {
  const int r0 = blockIdx.x << 7;
  const int tid = threadIdx.x;
  int o[9];
#pragma unroll
  for (int e = 0; e < 9; ++e) o[e] = off[e];
  for (int rr = 0; rr < 128; ++rr) {
    const int r = r0 + rr;
    if (r >= o[8]) return;           // uniform across block
    int e = 0;
    while (o[e + 1] <= r) ++e;
    if (r < o[e] + counts[e]) continue;  // real row
    ((ushort4*)(Xg + (size_t)r * DDIM))[tid] = make_ushort4(0, 0, 0, 0);
  }
}

// ---------------- grouped GEMM: C = [gelu](A @ Bw[e] + bias[e]) ----------------
// A: [rows][KTOT] bf16 (expert-segmented, 128-padded). Bw: [E][KTOT][N] fp32.
// 128x128 tile, BK=64, 4 waves, 16x16x32 bf16 MFMA, 4x4 acc tiles per wave.
// LDS tiles (both n/m-major): Tile[row][chunk] 16B chunks, swizzled
//   pos = chunk ^ ((row ^ (row>>3)) & 7)  -> <=2-way conflicts on reads & writes.
template <int KTOT, int N, bool GELU>
__global__ __launch_bounds__(256, 2)
void moe_gemm(const unsigned short* __restrict__ A, const float* __restrict__ Bw,
              const float* __restrict__ bias, unsigned short* __restrict__ C,
              const int* __restrict__ off) {
  __shared__ unsigned short As[128 * 64];
  __shared__ unsigned short Bs[128 * 64];

  const int tiles = off[8] >> 7;
  const int mt = blockIdx.x;
  if (mt >= tiles) return;
  const int row0 = mt << 7;
  int e = 0;
  while (off[e + 1] <= row0) ++e;
  const int n0 = blockIdx.y * 128;

  const float* Bp = Bw + (size_t)e * KTOT * N + n0;
  const float* biasp = bias + (size_t)e * N + n0;

  const int tid = threadIdx.x;
  const int wave = tid >> 6, lane = tid & 63;
  const int qd = lane >> 4, ln = lane & 15;
  const int wm = (wave & 1) << 6, wn = (wave >> 1) << 6;

  const int kg = tid >> 5;          // 0..7  (k-chunk this thread stages for B)
  const int nb = (tid & 31) << 2;   // 0..124 (4 consecutive n columns)

  f32x4 acc[4][4] = {};

  for (int kb = 0; kb < KTOT / 64; ++kb) {
    __syncthreads();
    // ---- A stage: 16 KB via global_load_lds width=16 ----
#pragma unroll
    for (int rr = 0; rr < 4; ++rr) {
      const int p = rr * 256 + tid;          // chunk id 0..1023
      const int r = p >> 3, q = p & 7;
      const int gq = q ^ ((r ^ (r >> 3)) & 7);
      const unsigned short* gs = A + (size_t)(row0 + r) * KTOT + kb * 64 + gq * 8;
      unsigned short* ls = As + (size_t)(p & ~63) * 8;  // wave-uniform base
      async_cp16(gs, ls);
    }
    // ---- B stage: fp32 load, bf16 convert, transpose to n-major LDS ----
    {
      const float* bs = Bp + (size_t)(kb * 64 + kg * 8) * N + nb;
      unsigned short u[4][8];
#pragma unroll
      for (int kk = 0; kk < 8; ++kk) {
        const float4 f = *(const float4*)(bs + (size_t)kk * N);
        u[0][kk] = f2bf(f.x); u[1][kk] = f2bf(f.y);
        u[2][kk] = f2bf(f.z); u[3][kk] = f2bf(f.w);
      }
#pragma unroll
      for (int c = 0; c < 4; ++c) {
        const int n = nb + c;
        const int pos = kg ^ ((n ^ (n >> 3)) & 7);
        uint4 P;
        P.x = (unsigned)u[c][0] | ((unsigned)u[c][1] << 16);
        P.y = (unsigned)u[c][2] | ((unsigned)u[c][3] << 16);
        P.z = (unsigned)u[c][4] | ((unsigned)u[c][5] << 16);
        P.w = (unsigned)u[c][6] | ((unsigned)u[c][7] << 16);
        *(uint4*)(Bs + ((size_t)n * 8 + pos) * 8) = P;
      }
    }
    __syncthreads();
    // ---- compute: 2 k-steps x 16 MFMA ----
#pragma unroll
    for (int s = 0; s < 2; ++s) {
      bf16x8 a[4], b[4];
#pragma unroll
      for (int i = 0; i < 4; ++i) {
        const int m = wm + i * 16 + ln;
        const int pos = (s * 4 + qd) ^ ((m ^ (m >> 3)) & 7);
        a[i] = *(const bf16x8*)(As + ((size_t)m * 8 + pos) * 8);
      }
#pragma unroll
      for (int j = 0; j < 4; ++j) {
        const int n = wn + j * 16 + ln;
        const int pos = (s * 4 + qd) ^ ((n ^ (n >> 3)) & 7);
        b[j] = *(const bf16x8*)(Bs + ((size_t)n * 8 + pos) * 8);
      }
#pragma unroll
      for (int i = 0; i < 4; ++i)
#pragma unroll
        for (int j = 0; j < 4; ++j)
          acc[i][j] = __builtin_amdgcn_mfma_f32_16x16x32_bf16(a[i], b[j], acc[i][j], 0, 0, 0);
    }
  }

  // ---- epilogue: bias (+gelu) -> bf16 C ----
#pragma unroll
  for (int j = 0; j < 4; ++j) {
    const int cn = wn + j * 16 + ln;
    const float bv = biasp[cn];
#pragma unroll
    for (int i = 0; i < 4; ++i) {
#pragma unroll
      for (int r = 0; r < 4; ++r) {
        const int gm = row0 + wm + i * 16 + qd * 4 + r;
        float v = acc[i][j][r] + bv;
        if (GELU) v = 0.5f * v * (1.f + erff(v * 0.70710678118654752f));
        C[(size_t)gm * N + n0 + cn] = f2bf(v);
      }
    }
  }
}

// ---------------- combine: out[t] = p0*y[s0] + p1*y[s1] ----------------
__global__ __launch_bounds__(256)
void moe_combine(const unsigned short* __restrict__ Ys,
                 const float* __restrict__ tk_prob,
                 const int* __restrict__ slot_of, float* __restrict__ out) {
  const int t = blockIdx.x;
  const int tid = threadIdx.x;
  const float p0 = tk_prob[2 * t], p1 = tk_prob[2 * t + 1];
  const int s0 = slot_of[2 * t], s1 = slot_of[2 * t + 1];
  const int d = tid * 4;
  const ushort4 a = *(const ushort4*)(Ys + (size_t)s0 * DDIM + d);
  const ushort4 b = *(const ushort4*)(Ys + (size_t)s1 * DDIM + d);
  float4 o;
  o.x = p0 * bf2f(a.x) + p1 * bf2f(b.x);
  o.y = p0 * bf2f(a.y) + p1 * bf2f(b.y);
  o.z = p0 * bf2f(a.z) + p1 * bf2f(b.z);
  o.w = p0 * bf2f(a.w) + p1 * bf2f(b.w);
  *(float4*)(out + (size_t)t * DDIM + d) = o;
}

extern "C" void kernel_launch(void* const* d_in, const int* in_sizes, int n_in,
                              void* d_out, int out_size, void* d_ws, size_t ws_size,
                              hipStream_t stream) {
  const float* x  = (const float*)d_in[0];
  const float* rw = (const float*)d_in[1];
  const float* w1 = (const float*)d_in[2];
  const float* b1 = (const float*)d_in[3];
  const float* w2 = (const float*)d_in[4];
  const float* b2 = (const float*)d_in[5];
  float* out = (float*)d_out;

  // workspace layout (needs ~113.4 MB)
  char* w = (char*)d_ws;
  int*   counts   = (int*)(w + 0);        // 8
  int*   cursor   = (int*)(w + 64);       // 8
  int*   off      = (int*)(w + 128);      // 9
  float* meanprob = (float*)(w + 192);    // 8
  int*   tk_idx   = (int*)(w + 256);                    // 8192 ints
  float* tk_prob  = (float*)(w + 33024);                // 8192 floats
  int*   slot_of  = (int*)(w + 65792);                  // 8192 ints
  unsigned short* Xg = (unsigned short*)(w + 98816);    // [9216][1024] bf16
  unsigned short* Hs = (unsigned short*)(w + 18973184); // [9216][4096] bf16
  unsigned short* Ys = (unsigned short*)(w + 94470656); // [9216][1024] bf16

  hipMemsetAsync(d_ws, 0, 256, stream);  // counts/cursor/off/meanprob
  moe_router<<<dim3(T_TOKENS / 4), dim3(256), 0, stream>>>(x, rw, tk_idx, tk_prob,
                                                           counts, meanprob);
  moe_prep<<<dim3(1), dim3(64), 0, stream>>>(counts, cursor, off, meanprob,
                                             out + (size_t)T_TOKENS * DDIM);
  moe_scatter<<<dim3(T_TOKENS), dim3(64), 0, stream>>>(x, tk_idx, cursor, slot_of, Xg);
  moe_padzero<<<dim3(MAXTILES), dim3(256), 0, stream>>>(off, counts, Xg);
  moe_gemm<DDIM, HDIM, true><<<dim3(MAXTILES, HDIM / 128), dim3(256), 0, stream>>>(
      Xg, w1, b1, Hs, off);
  moe_gemm<HDIM, DDIM, false><<<dim3(MAXTILES, DDIM / 128), dim3(256), 0, stream>>>(
      Hs, w2, b2, Ys, off);
  moe_combine<<<dim3(T_TOKENS), dim3(256), 0, stream>>>(Ys, tk_prob, slot_of, out);
}

// Round 2
// 590.136 us; speedup vs baseline: 1.4621x; 1.4621x over previous
//
#include <hip/hip_runtime.h>
#include <cstdint>
#include <cstddef>

// Problem constants
#define T_TOKENS 4096   // B*S
#define DDIM     1024
#define HDIM     4096
#define NEXP     8
#define MAXROWS  9216   // 8192 slots + 8*128 padding worst case
#define MAXTILES 72     // MAXROWS/128

typedef __attribute__((ext_vector_type(8))) short bf16x8;
typedef __attribute__((ext_vector_type(4))) float f32x4;

__device__ __forceinline__ unsigned short f2bf(float x) {
  union { float f; unsigned int u; } v; v.f = x;
  unsigned int r = v.u + 0x7fffu + ((v.u >> 16) & 1u);   // RNE
  return (unsigned short)(r >> 16);
}
__device__ __forceinline__ float bf2f(unsigned short b) {
  union { unsigned int u; float f; } v; v.u = ((unsigned int)b) << 16;
  return v.f;
}
__device__ __forceinline__ void async_cp16(const void* g, void* l) {
  __builtin_amdgcn_global_load_lds(
      (__attribute__((address_space(1))) void*)g,
      (__attribute__((address_space(3))) void*)l, 16, 0, 0);
}
__device__ __forceinline__ int swz(int r) { return (r ^ (r >> 3)) & 7; }

// ---------------- router: logits, softmax, top-2, stats ----------------
__global__ __launch_bounds__(256)
void moe_router(const float* __restrict__ x, const float* __restrict__ rw,
                int* __restrict__ tk_idx, float* __restrict__ tk_prob,
                int* __restrict__ counts, float* __restrict__ meanprob) {
  __shared__ float sp[NEXP];
  __shared__ int   sc[NEXP];
  const int tid = threadIdx.x;
  if (tid < NEXP) { sp[tid] = 0.f; sc[tid] = 0; }
  __syncthreads();
  const int wave = tid >> 6, lane = tid & 63;
  const int t = blockIdx.x * 4 + wave;
  float acc[NEXP] = {};
  for (int i = 0; i < 16; ++i) {
    const int d = i * 64 + lane;
    const float xv = x[(size_t)t * DDIM + d];
#pragma unroll
    for (int e = 0; e < NEXP; ++e) acc[e] += xv * rw[e * DDIM + d];
  }
#pragma unroll
  for (int e = 0; e < NEXP; ++e) {
#pragma unroll
    for (int m = 32; m >= 1; m >>= 1) acc[e] += __shfl_xor(acc[e], m);
  }
  if (lane == 0) {
    float mx = acc[0];
#pragma unroll
    for (int e = 1; e < NEXP; ++e) mx = fmaxf(mx, acc[e]);
    float p[NEXP], s = 0.f;
#pragma unroll
    for (int e = 0; e < NEXP; ++e) { p[e] = expf(acc[e] - mx); s += p[e]; }
    const float inv = 1.f / s;
#pragma unroll
    for (int e = 0; e < NEXP; ++e) p[e] *= inv;
    int i0 = 0;
#pragma unroll
    for (int e = 1; e < NEXP; ++e) if (p[e] > p[i0]) i0 = e;
    int i1 = (i0 == 0) ? 1 : 0;
#pragma unroll
    for (int e = 0; e < NEXP; ++e) if (e != i0 && p[e] > p[i1]) i1 = e;
    const float dn = 1.f / (p[i0] + p[i1] + 1e-8f);
    tk_idx[2 * t] = i0; tk_idx[2 * t + 1] = i1;
    tk_prob[2 * t] = p[i0] * dn; tk_prob[2 * t + 1] = p[i1] * dn;
#pragma unroll
    for (int e = 0; e < NEXP; ++e) atomicAdd(&sp[e], p[e]);
    atomicAdd(&sc[i0], 1); atomicAdd(&sc[i1], 1);
  }
  __syncthreads();
  if (tid < NEXP) {
    atomicAdd(&counts[tid], sc[tid]);
    atomicAdd(&meanprob[tid], sp[tid]);
  }
}

// ------- assign: offsets + loss + deterministic slot assignment (no atomics) -------
// grid = NEXP blocks x 256. Block e scans all T*K entries, prefix-sums matches.
__global__ __launch_bounds__(256)
void moe_assign(const int* __restrict__ counts, const int* __restrict__ tk_idx,
                int* __restrict__ slot_of, int* __restrict__ off_out,
                const float* __restrict__ meanprob, float* __restrict__ loss_out) {
  const int e = blockIdx.x;
  const int tid = threadIdx.x;
  int off[NEXP + 1];
  off[0] = 0;
#pragma unroll
  for (int i = 0; i < NEXP; ++i) off[i + 1] = off[i] + ((counts[i] + 127) & ~127);
  if (e == 0 && tid == 0) {
#pragma unroll
    for (int i = 0; i <= NEXP; ++i) off_out[i] = off[i];
    float loss = 0.f;
#pragma unroll
    for (int i = 0; i < NEXP; ++i) loss += meanprob[i] * (float)counts[i];
    loss_out[0] = loss * (8.f / (4096.f * 8192.f));
  }
  __shared__ int wsum[4];
  int cursor = off[e];
  const int lane = tid & 63, w = tid >> 6;
  for (int i0 = 0; i0 < T_TOKENS * 2; i0 += 256) {
    const int idx = i0 + tid;
    const int match = (tk_idx[idx] == e) ? 1 : 0;
    const unsigned long long b = __ballot(match);
    if (lane == 0) wsum[w] = __popcll(b);
    __syncthreads();
    int wbase = cursor;
    for (int j = 0; j < 4; ++j) { if (j == w) break; wbase += wsum[j]; }
    if (match) slot_of[idx] = wbase + __popcll(b & ((1ull << lane) - 1ull));
    cursor += wsum[0] + wsum[1] + wsum[2] + wsum[3];
    __syncthreads();
  }
}

// ---------------- scatter: gather x rows -> bf16 slots ----------------
__global__ __launch_bounds__(256)
void moe_scatter(const float* __restrict__ x, const int* __restrict__ slot_of,
                 unsigned short* __restrict__ Xg) {
  const int wave = threadIdx.x >> 6, lane = threadIdx.x & 63;
  const int t = blockIdx.x * 4 + wave;
  const int pos0 = slot_of[2 * t], pos1 = slot_of[2 * t + 1];
#pragma unroll
  for (int i = 0; i < 4; ++i) {
    const int d4 = (i * 64 + lane) * 4;
    const float4 f = *(const float4*)(x + (size_t)t * DDIM + d4);
    ushort4 u;
    u.x = f2bf(f.x); u.y = f2bf(f.y); u.z = f2bf(f.z); u.w = f2bf(f.w);
    *(ushort4*)(Xg + (size_t)pos0 * DDIM + d4) = u;
    *(ushort4*)(Xg + (size_t)pos1 * DDIM + d4) = u;
  }
}

// ------- convert+transpose: fp32 [E][K][N] -> bf16 [E][N][K] -------
__global__ __launch_bounds__(256)
void moe_convw(const float* __restrict__ src, unsigned short* __restrict__ dst,
               int K, int N) {
  __shared__ unsigned short tile[64][72];
  const int n0 = blockIdx.x * 64, k0 = blockIdx.y * 64, e = blockIdx.z;
  const int tid = threadIdx.x;
  const float* s = src + ((size_t)e * K + k0) * N + n0;
#pragma unroll
  for (int p = 0; p < 4; ++p) {
    const int r = p * 16 + (tid >> 4);       // k within tile
    const int c = (tid & 15) * 4;            // n within tile
    const float4 f = *(const float4*)(s + (size_t)r * N + c);
    tile[r][c + 0] = f2bf(f.x); tile[r][c + 1] = f2bf(f.y);
    tile[r][c + 2] = f2bf(f.z); tile[r][c + 3] = f2bf(f.w);
  }
  __syncthreads();
#pragma unroll
  for (int p = 0; p < 4; ++p) {
    const int n = p * 16 + (tid >> 4);
    const int k = (tid & 15) * 4;
    ushort4 u;
    u.x = tile[k + 0][n]; u.y = tile[k + 1][n];
    u.z = tile[k + 2][n]; u.w = tile[k + 3][n];
    *(ushort4*)(dst + ((size_t)e * N + n0 + n) * K + k0 + k) = u;
  }
}

// ---------------- grouped GEMM: C = [gelu](A @ Bt[e]^T + bias[e]) ----------------
// A:  [rows][KTOT] bf16 (expert-segmented, 128-padded rows)
// Bt: [E][N][KTOT] bf16 (pre-transposed weights, n-major)
// Both operands staged via global_load_lds width=16 into XOR-swizzled LDS.
// 128x128 tile, BK=64, 4 waves, 16x16x32 bf16 MFMA, 4x4 frag tiles per wave.
template <int KTOT, int N, bool GELU>
__global__ __launch_bounds__(256, 4)
void moe_gemm(const unsigned short* __restrict__ A,
              const unsigned short* __restrict__ Bt,
              const float* __restrict__ bias, unsigned short* __restrict__ C,
              const int* __restrict__ off) {
  __shared__ unsigned short As[128 * 64];
  __shared__ unsigned short Bs[128 * 64];

  const int tiles = off[8] >> 7;
  const int mt = blockIdx.x;
  if (mt >= tiles) return;
  const int row0 = mt << 7;
  int e = 0;
  while (off[e + 1] <= row0) ++e;
  const int n0 = blockIdx.y * 128;

  const unsigned short* Ap = A + (size_t)row0 * KTOT;
  const unsigned short* Bp = Bt + ((size_t)e * N + n0) * KTOT;
  const float* biasp = bias + (size_t)e * N + n0;

  const int tid = threadIdx.x;
  const int wave = tid >> 6, lane = tid & 63;
  const int qd = lane >> 4, ln = lane & 15;
  const int wm = (wave & 1) << 6, wn = (wave >> 1) << 6;

  f32x4 acc[4][4] = {};

  for (int kb = 0; kb < KTOT / 64; ++kb) {
    __syncthreads();
    // stage A and B tiles: 16 KB each, 4 cp16/thread per operand
#pragma unroll
    for (int rr = 0; rr < 4; ++rr) {
      const int p = rr * 256 + tid;          // chunk id 0..1023
      const int r = p >> 3, q = p & 7;
      const int gq = q ^ swz(r);             // swizzled source chunk
      const size_t goff = (size_t)r * KTOT + kb * 64 + gq * 8;
      unsigned short* lbase = (unsigned short*)((p & ~63) * 16);
      async_cp16(Ap + goff, As + (size_t)(p & ~63) * 8);
      async_cp16(Bp + goff, Bs + (size_t)(p & ~63) * 8);
      (void)lbase;
    }
    __syncthreads();
    // compute: 2 k-steps x 16 MFMA
#pragma unroll
    for (int s = 0; s < 2; ++s) {
      bf16x8 a[4], b[4];
#pragma unroll
      for (int i = 0; i < 4; ++i) {
        const int m = wm + i * 16 + ln;
        const int pos = (s * 4 + qd) ^ swz(m);
        a[i] = *(const bf16x8*)(As + ((size_t)m * 8 + pos) * 8);
      }
#pragma unroll
      for (int j = 0; j < 4; ++j) {
        const int n = wn + j * 16 + ln;
        const int pos = (s * 4 + qd) ^ swz(n);
        b[j] = *(const bf16x8*)(Bs + ((size_t)n * 8 + pos) * 8);
      }
#pragma unroll
      for (int i = 0; i < 4; ++i)
#pragma unroll
        for (int j = 0; j < 4; ++j)
          acc[i][j] = __builtin_amdgcn_mfma_f32_16x16x32_bf16(a[i], b[j], acc[i][j], 0, 0, 0);
    }
  }

  // epilogue: bias (+gelu) -> bf16 C
#pragma unroll
  for (int j = 0; j < 4; ++j) {
    const int cn = wn + j * 16 + ln;
    const float bv = biasp[cn];
#pragma unroll
    for (int i = 0; i < 4; ++i) {
#pragma unroll
      for (int r = 0; r < 4; ++r) {
        const int gm = row0 + wm + i * 16 + qd * 4 + r;
        float v = acc[i][j][r] + bv;
        if (GELU) v = 0.5f * v * (1.f + erff(v * 0.70710678118654752f));
        C[(size_t)gm * N + n0 + cn] = f2bf(v);
      }
    }
  }
}

// ---------------- combine: out[t] = p0*y[s0] + p1*y[s1] ----------------
__global__ __launch_bounds__(256)
void moe_combine(const unsigned short* __restrict__ Ys,
                 const float* __restrict__ tk_prob,
                 const int* __restrict__ slot_of, float* __restrict__ out) {
  const int wave = threadIdx.x >> 6, lane = threadIdx.x & 63;
  const int t = blockIdx.x * 4 + wave;
  const float p0 = tk_prob[2 * t], p1 = tk_prob[2 * t + 1];
  const int s0 = slot_of[2 * t], s1 = slot_of[2 * t + 1];
#pragma unroll
  for (int i = 0; i < 4; ++i) {
    const int d = (i * 64 + lane) * 4;
    const ushort4 a = *(const ushort4*)(Ys + (size_t)s0 * DDIM + d);
    const ushort4 b = *(const ushort4*)(Ys + (size_t)s1 * DDIM + d);
    float4 o;
    o.x = p0 * bf2f(a.x) + p1 * bf2f(b.x);
    o.y = p0 * bf2f(a.y) + p1 * bf2f(b.y);
    o.z = p0 * bf2f(a.z) + p1 * bf2f(b.z);
    o.w = p0 * bf2f(a.w) + p1 * bf2f(b.w);
    *(float4*)(out + (size_t)t * DDIM + d) = o;
  }
}

extern "C" void kernel_launch(void* const* d_in, const int* in_sizes, int n_in,
                              void* d_out, int out_size, void* d_ws, size_t ws_size,
                              hipStream_t stream) {
  const float* x  = (const float*)d_in[0];
  const float* rw = (const float*)d_in[1];
  const float* w1 = (const float*)d_in[2];
  const float* b1 = (const float*)d_in[3];
  const float* w2 = (const float*)d_in[4];
  const float* b2 = (const float*)d_in[5];
  float* out = (float*)d_out;

  // workspace layout (~162 MB):
  //   Ys overlays Xg (Xg dead after gemm1); Bt reused for w1 then w2.
  char* w = (char*)d_ws;
  int*   counts   = (int*)(w + 0);        // 8
  int*   off      = (int*)(w + 64);       // 9
  float* meanprob = (float*)(w + 128);    // 8
  int*   tk_idx   = (int*)(w + 256);                    // 8192 ints
  float* tk_prob  = (float*)(w + 33024);                // 8192 floats
  int*   slot_of  = (int*)(w + 65792);                  // 8192 ints
  unsigned short* Xg = (unsigned short*)(w + 98816);    // [9216][1024] bf16
  unsigned short* Ys = Xg;                              // overlay (post-gemm1)
  unsigned short* Hs = (unsigned short*)(w + 18973184); // [9216][4096] bf16
  unsigned short* Bt = (unsigned short*)(w + 94470656); // [8][4096][1024] bf16

  hipMemsetAsync(d_ws, 0, 256, stream);  // counts/off/meanprob
  moe_router<<<dim3(T_TOKENS / 4), dim3(256), 0, stream>>>(x, rw, tk_idx, tk_prob,
                                                           counts, meanprob);
  moe_assign<<<dim3(NEXP), dim3(256), 0, stream>>>(counts, tk_idx, slot_of, off,
                                                   meanprob,
                                                   out + (size_t)T_TOKENS * DDIM);
  moe_scatter<<<dim3(T_TOKENS / 4), dim3(256), 0, stream>>>(x, slot_of, Xg);
  // w1 [E][D][H] -> Bt [E][H][D]
  moe_convw<<<dim3(HDIM / 64, DDIM / 64, NEXP), dim3(256), 0, stream>>>(w1, Bt, DDIM, HDIM);
  moe_gemm<DDIM, HDIM, true><<<dim3(MAXTILES, HDIM / 128), dim3(256), 0, stream>>>(
      Xg, Bt, b1, Hs, off);
  // w2 [E][H][D] -> Bt [E][D][H]
  moe_convw<<<dim3(DDIM / 64, HDIM / 64, NEXP), dim3(256), 0, stream>>>(w2, Bt, HDIM, DDIM);
  moe_gemm<HDIM, DDIM, false><<<dim3(MAXTILES, DDIM / 128), dim3(256), 0, stream>>>(
      Hs, Bt, b2, Ys, off);
  moe_combine<<<dim3(T_TOKENS / 4), dim3(256), 0, stream>>>(Ys, tk_prob, slot_of, out);
}